// Round 11
// baseline (1864.709 us; speedup 1.0000x reference)
//
#include <hip/hip_runtime.h>
#include <hip/hip_bf16.h>

typedef __attribute__((ext_vector_type(8))) short shortx8;
typedef __attribute__((ext_vector_type(4))) float f32x4;
typedef __attribute__((ext_vector_type(4))) unsigned short ushortx4;
typedef __attribute__((ext_vector_type(4))) unsigned int u32x4;

#define HDIM 512
#define DDIM 64
#define TSTEPS 512
#define NG 16      // groups (batch slices of 16)
#define NB 16      // batch per group
#define SPIN_LIMIT (1u << 18)

// ws byte offsets
#define OFF_WHH0 0u
#define OFF_W1   (512u * 1024u)
#define OFF_WIH0 (OFF_W1 + 1024u * 1024u)
#define OFF_B0   (OFF_WIH0 + 64u * 1024u)
#define OFF_B1   (OFF_B0 + 2048u)
#define OFF_H1G  (OFF_B1 + 2048u)             // NG*2*16KB = 512KB
#define OFF_H2G  (OFF_H1G + 512u * 1024u)     // 512KB
#define OFF_CNT  (OFF_H2G + 512u * 1024u)     // NG*128B

__device__ __forceinline__ unsigned short f2b(float f) {
    __hip_bfloat16 h = __float2bfloat16(f);
    return *reinterpret_cast<unsigned short*>(&h);
}
__device__ __forceinline__ float b2f(unsigned short s) {
    union { unsigned int u; float f; } cvt;
    cvt.u = ((unsigned int)s) << 16;
    return cvt.f;
}
__device__ __forceinline__ float fast_tanh(float v) {
    float e = __expf(2.f * v);
    return 1.f - 2.f * __builtin_amdgcn_rcpf(e + 1.f);
}

// ---- MALL-homed (Infinity-Cache-coherent) ops: sc0 sc1 = bypass L1+L2 ----
__device__ __forceinline__ void mall_store8(unsigned short* p, ushortx4 v) {
    asm volatile("global_store_dwordx2 %0, %1, off sc0 sc1" :: "v"(p), "v"(v) : "memory");
}
__device__ __forceinline__ shortx8 mall_load16(const unsigned short* p) {
    shortx8 r;
    asm volatile("global_load_dwordx4 %0, %1, off sc0 sc1" : "=v"(r) : "v"(p) : "memory");
    return r;   // NOT waited — caller must vm_drain() before use
}
__device__ __forceinline__ void vm_drain() {
    asm volatile("s_waitcnt vmcnt(0)" ::: "memory");
    __builtin_amdgcn_sched_barrier(0);
}
__device__ __forceinline__ void flag_store(unsigned int* p, unsigned int v) {
    asm volatile("global_store_dword %0, %1, off sc0 sc1" :: "v"(p), "v"(v) : "memory");
}
// Wait until the 3 PEER flags reach tgt (own flag excluded: own data already
// drained; skipping it avoids a self store->load MALL round-trip).
__device__ __forceinline__ bool poll_peers(const unsigned int* fp, int m,
                                           unsigned int tgt, bool bail) {
    if (bail) return false;
    unsigned it = 0;
    for (;;) {
        u32x4 f;
        asm volatile("global_load_dwordx4 %0, %1, off sc0 sc1\n\ts_waitcnt vmcnt(0)"
                     : "=v"(f) : "v"(fp) : "memory");
        bool ok = true;
        if (m != 0 && f[0] < tgt) ok = false;
        if (m != 1 && f[1] < tgt) ok = false;
        if (m != 2 && f[2] < tgt) ok = false;
        if (m != 3 && f[3] < tgt) ok = false;
        if (ok) return true;
        if (++it > SPIN_LIMIT) return false;
    }
}

// ---------------------------------------------------------------------------
// Prep: swizzle weights to MFMA A-fragment-major bf16; fuse biases; zero sync
// flags with sc0/sc1 stores (flags are MALL-homed).
// ---------------------------------------------------------------------------
__global__ void prep_kernel(const float* __restrict__ w_ih0, const float* __restrict__ w_hh0,
                            const float* __restrict__ w_ih1, const float* __restrict__ w_hh1,
                            const float* __restrict__ b_ih0, const float* __restrict__ b_hh0,
                            const float* __restrict__ b_ih1, const float* __restrict__ b_hh1,
                            unsigned short* __restrict__ whh0_sw,
                            unsigned short* __restrict__ w1_sw,
                            unsigned short* __restrict__ wih0_sw,
                            float* __restrict__ bias0, float* __restrict__ bias1,
                            unsigned int* __restrict__ cnt)
{
    int idx = blockIdx.x * blockDim.x + threadIdx.x;
    int stride = gridDim.x * blockDim.x;

    for (int i = idx; i < 32 * 16 * 64; i += stride) {
        int l = i & 63, kb = (i >> 6) & 15, mt = i >> 10;
        int row = mt * 16 + (l & 15);
        int k0 = kb * 32 + (l >> 4) * 8;
        unsigned short* o = whh0_sw + (size_t)i * 8;
        #pragma unroll
        for (int j = 0; j < 8; ++j) o[j] = f2b(w_hh0[row * HDIM + k0 + j]);
    }
    for (int i = idx; i < 32 * 32 * 64; i += stride) {
        int l = i & 63, kb = (i >> 6) & 31, mt = i >> 11;
        int row = mt * 16 + (l & 15);
        int k0 = kb * 32 + (l >> 4) * 8;
        unsigned short* o = w1_sw + (size_t)i * 8;
        #pragma unroll
        for (int j = 0; j < 8; ++j) {
            int kk = k0 + j;
            float v = (kk < HDIM) ? w_ih1[row * HDIM + kk] : w_hh1[row * HDIM + (kk - HDIM)];
            o[j] = f2b(v);
        }
    }
    for (int i = idx; i < 32 * 2 * 64; i += stride) {
        int l = i & 63, kb = (i >> 6) & 1, mt = i >> 7;
        int row = mt * 16 + (l & 15);
        int k0 = kb * 32 + (l >> 4) * 8;
        unsigned short* o = wih0_sw + (size_t)i * 8;
        #pragma unroll
        for (int j = 0; j < 8; ++j) o[j] = f2b(w_ih0[row * DDIM + k0 + j]);
    }
    for (int i = idx; i < HDIM; i += stride) {
        bias0[i] = b_ih0[i] + b_hh0[i];
        bias1[i] = b_ih1[i] + b_hh1[i];
    }
    if (idx < NG * 32) {
        unsigned int z = 0;
        unsigned int* p = cnt + idx;
        asm volatile("global_store_dword %0, %1, off sc0 sc1" :: "v"(p), "v"(z) : "memory");
    }
}

// ---------------------------------------------------------------------------
// 16 groups x 4 CUs; CU m owns rows [128m,128m+128); weights register-resident.
// ONE sync round per step (round-6-proven protocol): iteration t computes
// h1(t+1) (A1) AND h2(t) (A3) from local LDS, publishes both, drains, then a
// flag round. NEW vs round 6: only WAVE 0 polls the MALL flag line; it
// broadcasts via an LDS token (WG-scope release/acquire). Other waves spin on
// LDS (~120cy granularity vs ~1300cy MALL sample quantization), eliminating
// the cross-wave poll-exit spread that the end barrier previously absorbed.
// Safety: token ==> wave0 observed peer flags at MALL ==> peer data landed
// (peers drain before flagging) ==> any later-issued stage load is fresh
// (MALL state is monotone). Same argument round 6 already relies on.
// ---------------------------------------------------------------------------
__global__ __launch_bounds__(256, 1) void rnn_1sync(
    const float* __restrict__ x,
    const unsigned short* __restrict__ whh0_sw,
    const unsigned short* __restrict__ w1_sw,
    const unsigned short* __restrict__ wih0_sw,
    const float* __restrict__ bias0,
    const float* __restrict__ bias1,
    const float* __restrict__ w_lin,
    const float* __restrict__ b_lin,
    unsigned short* __restrict__ h1G,
    unsigned short* __restrict__ h2G,
    unsigned int* __restrict__ cnt,
    float* __restrict__ out)
{
    __shared__ unsigned short h1L[2][8192];
    __shared__ unsigned short h2L[2][8192];
    __shared__ unsigned short xL[2][1024];
    __shared__ unsigned int go_token;

    const int tid  = threadIdx.x;
    const int w    = tid >> 6;
    const int lane = tid & 63;
    const int gq   = lane >> 4;
    const int col  = lane & 15;
    const int b    = blockIdx.x;
    const int g    = (b & 7) | ((b >> 5) << 3);   // 4 members per group (XCD-affine)
    const int m    = (b >> 3) & 3;

    const int mt0 = m * 8 + 2 * w, mt1 = mt0 + 1;
    const int lbase = gq * 128 + col * 8;
    const int dbase = (gq >> 1) * 128 + col * 8 + (gq & 1) * 4;

    unsigned int* flags = cnt + g * 32;           // 4 dwords in one 16B line

    if (tid == 0) go_token = 0u;

    // ---- weights -> registers, once; pinned ----
    shortx8 W0a[18], W0b[18], W1a[32], W1b[32];
    #pragma unroll
    for (int kb = 0; kb < 16; ++kb) {
        W0a[kb] = *(const shortx8*)(whh0_sw + (((size_t)(mt0 * 16 + kb)) << 9) + lane * 8);
        W0b[kb] = *(const shortx8*)(whh0_sw + (((size_t)(mt1 * 16 + kb)) << 9) + lane * 8);
    }
    #pragma unroll
    for (int kx = 0; kx < 2; ++kx) {
        W0a[16 + kx] = *(const shortx8*)(wih0_sw + (((size_t)(mt0 * 2 + kx)) << 9) + lane * 8);
        W0b[16 + kx] = *(const shortx8*)(wih0_sw + (((size_t)(mt1 * 2 + kx)) << 9) + lane * 8);
    }
    #pragma unroll
    for (int kb = 0; kb < 32; ++kb) {
        W1a[kb] = *(const shortx8*)(w1_sw + (((size_t)(mt0 * 32 + kb)) << 9) + lane * 8);
        W1b[kb] = *(const shortx8*)(w1_sw + (((size_t)(mt1 * 32 + kb)) << 9) + lane * 8);
    }
    #pragma unroll
    for (int i = 0; i < 18; ++i) { asm volatile("" : "+v"(W0a[i]), "+v"(W0b[i])); }
    #pragma unroll
    for (int i = 0; i < 32; ++i) { asm volatile("" : "+v"(W1a[i]), "+v"(W1b[i])); }

    f32x4 b0a = *(const f32x4*)(bias0 + mt0 * 16 + gq * 4);
    f32x4 b0b = *(const f32x4*)(bias0 + mt1 * 16 + gq * 4);
    f32x4 b1a = *(const f32x4*)(bias1 + mt0 * 16 + gq * 4);
    f32x4 b1b = *(const f32x4*)(bias1 + mt1 * 16 + gq * 4);

    const int bb = tid >> 4, d4 = (tid & 15) * 4;
    const int xo = ((d4 >> 3) * 16 + bb) * 8 + (d4 & 7);
    const float* xrow = x + (size_t)(g * NB + bb) * TSTEPS * DDIM + d4;
    bool bail = false;

    // ---- prologue: xL[0]=x(0), xL[1]=x(1); h2(-1)=0; h1(0) compute+exchange
    {
        f32x4 x0 = *(const f32x4*)(xrow);
        f32x4 x1 = *(const f32x4*)(xrow + DDIM);
        ushortx4 o0, o1;
        #pragma unroll
        for (int j = 0; j < 4; ++j) { o0[j] = f2b(x0[j]); o1[j] = f2b(x1[j]); }
        *(ushortx4*)&xL[0][xo] = o0;
        *(ushortx4*)&xL[1][xo] = o1;
        shortx8 zz = {0, 0, 0, 0, 0, 0, 0, 0};
        for (int i = tid * 8; i < 8192; i += 2048) *(shortx8*)&h2L[1][i] = zz;
    }
    __syncthreads();
    {
        unsigned short* h1G0 = h1G + (size_t)(g * 2 + 0) * 8192;
        f32x4 acc0 = b0a, acc1 = b0b;
        #pragma unroll
        for (int kx = 0; kx < 2; ++kx) {
            shortx8 bf = *(const shortx8*)&xL[0][kx * 512 + lbase];
            acc0 = __builtin_amdgcn_mfma_f32_16x16x32_bf16(W0a[16 + kx], bf, acc0, 0, 0, 0);
            acc1 = __builtin_amdgcn_mfma_f32_16x16x32_bf16(W0b[16 + kx], bf, acc1, 0, 0, 0);
        }
        ushortx4 o0, o1;
        #pragma unroll
        for (int j = 0; j < 4; ++j) { o0[j] = f2b(fast_tanh(acc0[j])); o1[j] = f2b(fast_tanh(acc1[j])); }
        mall_store8(h1G0 + mt0 * 256 + dbase, o0);
        mall_store8(h1G0 + mt1 * 256 + dbase, o1);
        vm_drain();
        __syncthreads();
        if (tid == 0) flag_store(flags + m, 1u);
        if (!poll_peers(flags, m, 1u, bail)) bail = true;
        int o = tid * 8;
        shortx8 v0 = mall_load16(h1G0 + o);
        shortx8 v1 = mall_load16(h1G0 + o + 2048);
        shortx8 v2 = mall_load16(h1G0 + o + 4096);
        shortx8 v3 = mall_load16(h1G0 + o + 6144);
        vm_drain();
        *(shortx8*)&h1L[0][o]        = v0;
        *(shortx8*)&h1L[0][o + 2048] = v1;
        *(shortx8*)&h1L[0][o + 4096] = v2;
        *(shortx8*)&h1L[0][o + 6144] = v3;
    }
    __syncthreads();

    // ---- main loop: iteration t computes h1(t+1) AND h2(t); one sync round ----
    for (int t = 0; t < TSTEPS - 1; ++t) {
        const int pc = t & 1, pn = pc ^ 1;
        unsigned short* h1Gn = h1G + (size_t)(g * 2 + pn) * 8192;  // h1(t+1)
        unsigned short* h2Gc = h2G + (size_t)(g * 2 + pc) * 8192;  // h2(t)

        const bool havex = (t + 2 < TSTEPS);
        f32x4 xv;
        if (havex) xv = *(const f32x4*)(xrow + (size_t)(t + 2) * DDIM);

        // fused A1 + A3-part1: one h1L read feeds 4 MFMAs
        f32x4 acc0 = b0a, acc1 = b0b, e0 = b1a, e1 = b1b;
        #pragma unroll
        for (int kb = 0; kb < 16; ++kb) {
            shortx8 bf = *(const shortx8*)&h1L[pc][kb * 512 + lbase];
            acc0 = __builtin_amdgcn_mfma_f32_16x16x32_bf16(W0a[kb], bf, acc0, 0, 0, 0);
            acc1 = __builtin_amdgcn_mfma_f32_16x16x32_bf16(W0b[kb], bf, acc1, 0, 0, 0);
            e0   = __builtin_amdgcn_mfma_f32_16x16x32_bf16(W1a[kb], bf, e0, 0, 0, 0);
            e1   = __builtin_amdgcn_mfma_f32_16x16x32_bf16(W1b[kb], bf, e1, 0, 0, 0);
        }
        #pragma unroll
        for (int kx = 0; kx < 2; ++kx) {
            shortx8 bf = *(const shortx8*)&xL[pn][kx * 512 + lbase];
            acc0 = __builtin_amdgcn_mfma_f32_16x16x32_bf16(W0a[16 + kx], bf, acc0, 0, 0, 0);
            acc1 = __builtin_amdgcn_mfma_f32_16x16x32_bf16(W0b[16 + kx], bf, acc1, 0, 0, 0);
        }
        #pragma unroll
        for (int kb = 0; kb < 16; ++kb) {
            shortx8 bf = *(const shortx8*)&h2L[pn][kb * 512 + lbase];
            e0 = __builtin_amdgcn_mfma_f32_16x16x32_bf16(W1a[16 + kb], bf, e0, 0, 0, 0);
            e1 = __builtin_amdgcn_mfma_f32_16x16x32_bf16(W1b[16 + kb], bf, e1, 0, 0, 0);
        }

        // publish h1(t+1) and h2(t)
        {
            ushortx4 o0, o1, p0, p1;
            #pragma unroll
            for (int j = 0; j < 4; ++j) {
                o0[j] = f2b(fast_tanh(acc0[j])); o1[j] = f2b(fast_tanh(acc1[j]));
                p0[j] = f2b(fast_tanh(e0[j]));   p1[j] = f2b(fast_tanh(e1[j]));
            }
            mall_store8(h1Gn + mt0 * 256 + dbase, o0);
            mall_store8(h1Gn + mt1 * 256 + dbase, o1);
            mall_store8(h2Gc + mt0 * 256 + dbase, p0);
            mall_store8(h2Gc + mt1 * 256 + dbase, p1);
        }
        if (havex) {
            ushortx4 ox;
            #pragma unroll
            for (int j = 0; j < 4; ++j) ox[j] = f2b(xv[j]);
            *(ushortx4*)&xL[pc][xo] = ox;
        }
        vm_drain();
        __syncthreads();

        // one flag round: tid0 stores own; WAVE 0 polls peers, LDS-broadcasts
        const unsigned int tgt = (unsigned int)(t + 2);
        if (tid == 0) flag_store(flags + m, tgt);
        if (w == 0) {
            if (!poll_peers(flags, m, tgt, bail)) bail = true;
            if (lane == 0)
                __hip_atomic_store(&go_token, tgt, __ATOMIC_RELEASE,
                                   __HIP_MEMORY_SCOPE_WORKGROUP);
        } else {
            unsigned it = 0;
            while (__hip_atomic_load(&go_token, __ATOMIC_ACQUIRE,
                                     __HIP_MEMORY_SCOPE_WORKGROUP) < tgt) {
                if (++it > SPIN_LIMIT) { bail = true; break; }
            }
        }

        // stage h1(t+1) -> h1L[pn], h2(t) -> h2L[pc]  (8 loads in flight)
        const int o = tid * 8;
        shortx8 va0 = mall_load16(h1Gn + o);
        shortx8 va1 = mall_load16(h1Gn + o + 2048);
        shortx8 va2 = mall_load16(h1Gn + o + 4096);
        shortx8 va3 = mall_load16(h1Gn + o + 6144);
        shortx8 vb0 = mall_load16(h2Gc + o);
        shortx8 vb1 = mall_load16(h2Gc + o + 2048);
        shortx8 vb2 = mall_load16(h2Gc + o + 4096);
        shortx8 vb3 = mall_load16(h2Gc + o + 6144);
        vm_drain();
        *(shortx8*)&h1L[pn][o]        = va0;
        *(shortx8*)&h1L[pn][o + 2048] = va1;
        *(shortx8*)&h1L[pn][o + 4096] = va2;
        *(shortx8*)&h1L[pn][o + 6144] = va3;
        *(shortx8*)&h2L[pc][o]        = vb0;
        *(shortx8*)&h2L[pc][o + 2048] = vb1;
        *(shortx8*)&h2L[pc][o + 4096] = vb2;
        *(shortx8*)&h2L[pc][o + 6144] = vb3;
        __syncthreads();
    }

    // ---- epilogue: h2(511) = tanh(w_ih1 @ h1(511) + w_hh1 @ h2(510) + b1) ----
    {
        unsigned short* h2Gc = h2G + (size_t)(g * 2 + 1) * 8192;
        f32x4 e0 = b1a, e1 = b1b;
        #pragma unroll
        for (int kb = 0; kb < 16; ++kb) {
            shortx8 bf = *(const shortx8*)&h1L[1][kb * 512 + lbase];
            e0 = __builtin_amdgcn_mfma_f32_16x16x32_bf16(W1a[kb], bf, e0, 0, 0, 0);
            e1 = __builtin_amdgcn_mfma_f32_16x16x32_bf16(W1b[kb], bf, e1, 0, 0, 0);
        }
        #pragma unroll
        for (int kb = 0; kb < 16; ++kb) {
            shortx8 bf = *(const shortx8*)&h2L[0][kb * 512 + lbase];
            e0 = __builtin_amdgcn_mfma_f32_16x16x32_bf16(W1a[16 + kb], bf, e0, 0, 0, 0);
            e1 = __builtin_amdgcn_mfma_f32_16x16x32_bf16(W1b[16 + kb], bf, e1, 0, 0, 0);
        }
        ushortx4 o0, o1;
        #pragma unroll
        for (int j = 0; j < 4; ++j) { o0[j] = f2b(fast_tanh(e0[j])); o1[j] = f2b(fast_tanh(e1[j])); }
        mall_store8(h2Gc + mt0 * 256 + dbase, o0);
        mall_store8(h2Gc + mt1 * 256 + dbase, o1);
        vm_drain();
        __syncthreads();
        if (tid == 0) flag_store(flags + m, (unsigned int)(TSTEPS + 1));

        // final linear on member 0
        if (m == 0) {
            if (!poll_peers(flags, m, (unsigned int)(TSTEPS + 1), bail)) bail = true;
            #pragma unroll
            for (int r = 0; r < 4; ++r) {
                int bx = w * 4 + r;
                shortx8 hv = mall_load16(h2Gc + lane * 128 + bx * 8);
                vm_drain();
                float s = 0.f;
                #pragma unroll
                for (int j = 0; j < 8; ++j)
                    s += b2f((unsigned short)hv[j]) * w_lin[lane * 8 + j];
                #pragma unroll
                for (int off = 32; off; off >>= 1) s += __shfl_xor(s, off);
                if (lane == 0) out[g * NB + bx] = s + b_lin[0];
            }
        }
    }
    if (bail && tid == 0 && g == 0 && m == 0) out[0] = out[0];  // keep bail live
}

extern "C" void kernel_launch(void* const* d_in, const int* in_sizes, int n_in,
                              void* d_out, int out_size, void* d_ws, size_t ws_size,
                              hipStream_t stream) {
    const float* x     = (const float*)d_in[0];
    const float* w_ih0 = (const float*)d_in[1];
    const float* w_hh0 = (const float*)d_in[2];
    const float* b_ih0 = (const float*)d_in[3];
    const float* b_hh0 = (const float*)d_in[4];
    const float* w_ih1 = (const float*)d_in[5];
    const float* w_hh1 = (const float*)d_in[6];
    const float* b_ih1 = (const float*)d_in[7];
    const float* b_hh1 = (const float*)d_in[8];
    const float* w_lin = (const float*)d_in[9];
    const float* b_lin = (const float*)d_in[10];
    float* out = (float*)d_out;

    char* ws = (char*)d_ws;
    unsigned short* whh0_sw = (unsigned short*)(ws + OFF_WHH0);
    unsigned short* w1_sw   = (unsigned short*)(ws + OFF_W1);
    unsigned short* wih0_sw = (unsigned short*)(ws + OFF_WIH0);
    float* bias0            = (float*)(ws + OFF_B0);
    float* bias1            = (float*)(ws + OFF_B1);
    unsigned short* h1G     = (unsigned short*)(ws + OFF_H1G);
    unsigned short* h2G     = (unsigned short*)(ws + OFF_H2G);
    unsigned int*   cnt     = (unsigned int*)(ws + OFF_CNT);

    prep_kernel<<<416, 256, 0, stream>>>(w_ih0, w_hh0, w_ih1, w_hh1,
                                         b_ih0, b_hh0, b_ih1, b_hh1,
                                         whh0_sw, w1_sw, wih0_sw, bias0, bias1, cnt);
    rnn_1sync<<<64, 256, 0, stream>>>(x, whh0_sw, w1_sw, wih0_sw, bias0, bias1,
                                      w_lin, b_lin, h1G, h2G, cnt, out);
}